// Round 3
// baseline (1501.857 us; speedup 1.0000x reference)
//
#include <hip/hip_runtime.h>
#include <cfloat>
#include <cmath>

#define HC 80   // H*C
#define HH 8    // heads
#define CC 10   // channels per head

// ---------------- CSR build ----------------

__global__ void hist_kernel(const int* __restrict__ dst, int* __restrict__ counts, int E) {
    int i = blockIdx.x * blockDim.x + threadIdx.x;
    int stride = gridDim.x * blockDim.x;
    for (; i < E; i += stride) atomicAdd(&counts[dst[i]], 1);
}

// single-block exclusive scan over n elements, writes out[0..n] (out[n] = total)
// shuffle-based: 3 barriers per 1024-chunk instead of ~20
__global__ void scan_kernel(const int* __restrict__ in, int* __restrict__ out, int n) {
    __shared__ int wsum[16];
    __shared__ int carry;
    if (threadIdx.x == 0) carry = 0;
    __syncthreads();
    int lane = threadIdx.x & 63, w = threadIdx.x >> 6;
    for (int base = 0; base < n; base += 1024) {
        int i = base + (int)threadIdx.x;
        int v = (i < n) ? in[i] : 0;
        int s = v;                              // wave inclusive scan
        #pragma unroll
        for (int off = 1; off < 64; off <<= 1) {
            int t = __shfl_up(s, off, 64);
            if (lane >= off) s += t;
        }
        if (lane == 63) wsum[w] = s;
        __syncthreads();
        if (w == 0) {                           // scan the 16 wave totals
            int ws = (lane < 16) ? wsum[lane] : 0;
            int ss = ws;
            #pragma unroll
            for (int off = 1; off < 16; off <<= 1) {
                int t = __shfl_up(ss, off, 64);
                if (lane >= off) ss += t;
            }
            if (lane < 16) wsum[lane] = ss - ws; // exclusive wave prefix
        }
        __syncthreads();
        int c = carry;
        if (i < n) out[i] = c + wsum[w] + s - v;
        __syncthreads();                         // all reads of carry/wsum done
        if (threadIdx.x == 1023) carry = c + wsum[15] + s;
    }
    __syncthreads();
    if (threadIdx.x == 0) out[n] = carry;
}

__global__ void scatter_kernel(const int* __restrict__ src, const int* __restrict__ dst,
                               int* __restrict__ cursor, int* __restrict__ csr, int E) {
    int i = blockIdx.x * blockDim.x + threadIdx.x;
    int stride = gridDim.x * blockDim.x;
    for (; i < E; i += stride) {
        int p = atomicAdd(&cursor[dst[i]], 1);
        csr[p] = src[i];
    }
}

// ---------------- dual GEMM: Yl = X@Wl, Yr = X@Wr  (X:[N,K], W:[K,80]) ----------------
// block = 128 threads = 2 waves over a 64-row tile. Lane = row. Wave 0 -> Yl, wave 1 -> Yr.
// W loads are wave-uniform -> s_load through scalar cache (16 B/load, not 1 KB/wave).
// X tile staged in LDS, stride K+4 so ds_read_b128 is cheap.

__global__ __launch_bounds__(128) void gemm_tile(
    const float* __restrict__ X, const float* __restrict__ Wl, const float* __restrict__ Wr,
    float* __restrict__ Yl, float* __restrict__ Yr, int N, int K)
{
    __shared__ float xs[64 * 132];          // K<=128, stride K+4
    const int tid = threadIdx.x;
    const int lane = tid & 63;
    const int wv = tid >> 6;
    const int base = blockIdx.x * 64;
    const int K4 = K >> 2;
    const int ldk = K + 4;

    const float4* X4 = (const float4*)X;
    for (int idx = tid; idx < 64 * K4; idx += 128) {
        int r = idx / K4, c = idx - r * K4;
        int n = base + r; if (n >= N) n = N - 1;   // clamp: safe garbage
        float4 v = X4[(size_t)n * K4 + c];
        *(float4*)&xs[r * ldk + 4 * c] = v;
    }
    __syncthreads();

    const float* W = wv ? Wr : Wl;
    float4 acc[20];
    #pragma unroll
    for (int j = 0; j < 20; ++j) acc[j] = make_float4(0.f, 0.f, 0.f, 0.f);

    const float* xrow = &xs[lane * ldk];
    for (int k4 = 0; k4 < K4; ++k4) {
        float4 xv = *(const float4*)&xrow[4 * k4];
        const float4* w0 = (const float4*)(W + (size_t)(4 * k4) * HC);
        #pragma unroll
        for (int kk = 0; kk < 4; ++kk) {
            float xk = (kk == 0) ? xv.x : (kk == 1) ? xv.y : (kk == 2) ? xv.z : xv.w;
            const float4* w = w0 + kk * 20;
            #pragma unroll
            for (int j = 0; j < 20; ++j) {
                acc[j].x += xk * w[j].x;
                acc[j].y += xk * w[j].y;
                acc[j].z += xk * w[j].z;
                acc[j].w += xk * w[j].w;
            }
        }
    }

    int n = base + lane;
    if (n < N) {
        float4* y = (float4*)((wv ? Yr : Yl) + (size_t)n * HC);
        #pragma unroll
        for (int j = 0; j < 20; ++j) y[j] = acc[j];
    }
}

// ---------------- fused per-node attention + softmax + aggregate + elu ----------------
// block = 128 threads = 8 head-groups of 16 lanes (10 active each).

__global__ __launch_bounds__(128) void aggregate_kernel(
    const float* __restrict__ xl, const float* __restrict__ xr,
    const int* __restrict__ csr, const int* __restrict__ offsets,
    const float* __restrict__ att, const float* __restrict__ bias,
    float* __restrict__ xout, int N) {
    int n = blockIdx.x;
    int tid = threadIdx.x;
    int h = tid >> 4;
    int c = tid & 15;
    bool active = c < CC;
    int d = h * CC + (active ? c : CC - 1);   // clamped for safe loads
    float mask = active ? 1.f : 0.f;
    float attv = att[d] * mask;               // inactive lanes contribute 0 to e
    float xrv = xr[(size_t)n * HC + d];
    int beg = offsets[n], end = offsets[n + 1];

    float m = -FLT_MAX, s = 0.f, acc = 0.f;
    for (int i = beg - 1; i < end; ++i) {
        int src = (i < beg) ? n : csr[i];     // iteration -1 = self loop
        float xlv = xl[(size_t)src * HC + d];
        float t = xlv + xrv;
        t = (t > 0.f) ? t : 0.2f * t;         // leaky_relu
        float ev = t * attv;
        ev += __shfl_xor(ev, 8, 16);          // sum over the 16-lane head group
        ev += __shfl_xor(ev, 4, 16);
        ev += __shfl_xor(ev, 2, 16);
        ev += __shfl_xor(ev, 1, 16);
        float mn = fmaxf(m, ev);
        float sc = __expf(m - mn);
        float p = __expf(ev - mn);
        s = s * sc + p;
        acc = acc * sc + p * xlv;
        m = mn;
    }
    if (active) {
        float o = acc / s + bias[d];
        xout[(size_t)n * HC + h * CC + c] = (o > 0.f) ? o : (__expf(o) - 1.f);  // elu
    }
}

extern "C" void kernel_launch(void* const* d_in, const int* in_sizes, int n_in,
                              void* d_out, int out_size, void* d_ws, size_t ws_size,
                              hipStream_t stream) {
    int N = out_size / HC;       // 100000
    int E = in_sizes[1] / 2;     // 1000000
    int F = in_sizes[0] / N;     // 128

    const float* x   = (const float*)d_in[0];
    const int*   ei  = (const int*)d_in[1];
    const float* Wl[3]  = {(const float*)d_in[2], (const float*)d_in[6],  (const float*)d_in[10]};
    const float* Wr[3]  = {(const float*)d_in[3], (const float*)d_in[7],  (const float*)d_in[11]};
    const float* att[3] = {(const float*)d_in[4], (const float*)d_in[8],  (const float*)d_in[12]};
    const float* bb[3]  = {(const float*)d_in[5], (const float*)d_in[9],  (const float*)d_in[13]};

    size_t NF = (size_t)N * HC;
    float* xl = (float*)d_ws;
    float* xr = xl + NF;
    float* xb = xr + NF;
    int* counts  = (int*)(xb + NF);
    int* offsets = counts + (N + 1);
    int* cursor  = offsets + (N + 1);
    int* csr     = cursor + N;

    const int* srcv = ei;
    const int* dstv = ei + E;

    // build dst-CSR (self loops handled implicitly in aggregate)
    hipMemsetAsync(counts, 0, (size_t)(N + 1) * sizeof(int), stream);
    hist_kernel<<<1024, 256, 0, stream>>>(dstv, counts, E);
    scan_kernel<<<1, 1024, 0, stream>>>(counts, offsets, N);
    hipMemcpyAsync(cursor, offsets, (size_t)N * sizeof(int), hipMemcpyDeviceToDevice, stream);
    scatter_kernel<<<1024, 256, 0, stream>>>(srcv, dstv, cursor, csr, E);

    for (int l = 0; l < 3; ++l) {
        const float* xin = (l == 0) ? x : xb;
        int K = (l == 0) ? F : HC;
        gemm_tile<<<(N + 63) / 64, 128, 0, stream>>>(xin, Wl[l], Wr[l], xl, xr, N, K);
        float* xout = (l == 2) ? (float*)d_out : xb;
        aggregate_kernel<<<N, 128, 0, stream>>>(xl, xr, csr, offsets, att[l], bb[l], xout, N);
    }
}

// Round 5
// 921.722 us; speedup vs baseline: 1.6294x; 1.6294x over previous
//
#include <hip/hip_runtime.h>
#include <cfloat>
#include <cmath>

#define HC 80   // H*C
#define HH 8    // heads
#define CC 10   // channels per head

// +4-float gap every 32 floats: spreads stride-32 column patterns across banks
#define GAP(c) ((c) + ((((c) >> 5)) << 2))

// ---------------- CSR build ----------------

__global__ void hist_kernel(const int* __restrict__ dst, int* __restrict__ counts, int E) {
    int i = blockIdx.x * blockDim.x + threadIdx.x;
    int stride = gridDim.x * blockDim.x;
    for (; i < E; i += stride) atomicAdd(&counts[dst[i]], 1);
}

__global__ void scan_kernel(const int* __restrict__ in, int* __restrict__ out, int n) {
    __shared__ int wsum[16];
    __shared__ int carry;
    if (threadIdx.x == 0) carry = 0;
    __syncthreads();
    int lane = threadIdx.x & 63, w = threadIdx.x >> 6;
    for (int base = 0; base < n; base += 1024) {
        int i = base + (int)threadIdx.x;
        int v = (i < n) ? in[i] : 0;
        int s = v;
        #pragma unroll
        for (int off = 1; off < 64; off <<= 1) {
            int t = __shfl_up(s, off, 64);
            if (lane >= off) s += t;
        }
        if (lane == 63) wsum[w] = s;
        __syncthreads();
        if (w == 0) {
            int ws = (lane < 16) ? wsum[lane] : 0;
            int ss = ws;
            #pragma unroll
            for (int off = 1; off < 16; off <<= 1) {
                int t = __shfl_up(ss, off, 64);
                if (lane >= off) ss += t;
            }
            if (lane < 16) wsum[lane] = ss - ws;
        }
        __syncthreads();
        int c = carry;
        if (i < n) out[i] = c + wsum[w] + s - v;
        __syncthreads();
        if (threadIdx.x == 1023) carry = c + wsum[15] + s;
    }
    __syncthreads();
    if (threadIdx.x == 0) out[n] = carry;
}

__global__ void scatter_kernel(const int* __restrict__ src, const int* __restrict__ dst,
                               int* __restrict__ cursor, int* __restrict__ csr, int E) {
    int i = blockIdx.x * blockDim.x + threadIdx.x;
    int stride = gridDim.x * blockDim.x;
    for (; i < E; i += stride) {
        int p = atomicAdd(&cursor[dst[i]], 1);
        csr[p] = src[i];
    }
}

// ---------------- dual GEMM: [Yl|Yr] = X @ [Wl|Wr]  (X:[N,K], W:[K,80] each) ----------------
// 320 threads, tile 128 rows x 160 cols, BK=16, thread tile 8x8.
// xs[k][GAP(row)], ws[k][GAP(col)] -> conflict-free ds_read_b128 in compute loop.

__global__ __launch_bounds__(320) void gemm_big(
    const float* __restrict__ X, const float* __restrict__ Wl, const float* __restrict__ Wr,
    float* __restrict__ Yl, float* __restrict__ Yr, int N, int K)
{
    __shared__ float xs[16 * 140];   // GAP(127)=139
    __shared__ float ws[16 * 176];   // GAP(159)=175
    const int tid = threadIdx.x;
    const int rt = tid / 20;         // 0..15
    const int cg = tid - rt * 20;    // 0..19
    const int r0 = rt * 8;
    const int c0 = cg * 8;
    const int rG0 = GAP(r0);
    const int cG0 = GAP(c0);
    const int base = blockIdx.x * 128;

    float4 acc[8][2];
    #pragma unroll
    for (int i = 0; i < 8; ++i) {
        acc[i][0] = make_float4(0.f, 0.f, 0.f, 0.f);
        acc[i][1] = make_float4(0.f, 0.f, 0.f, 0.f);
    }

    for (int k0 = 0; k0 < K; k0 += 16) {
        __syncthreads();
        // stage X tile (128 rows x 16 k) transposed into xs[k][GAP(r)]
        for (int idx = tid; idx < 512; idx += 320) {
            int r = idx >> 2, kc = (idx & 3) << 2;
            int n = base + r; if (n >= N) n = N - 1;
            float4 v = *(const float4*)(X + (size_t)n * K + k0 + kc);
            int rg = GAP(r);
            xs[(kc + 0) * 140 + rg] = v.x;
            xs[(kc + 1) * 140 + rg] = v.y;
            xs[(kc + 2) * 140 + rg] = v.z;
            xs[(kc + 3) * 140 + rg] = v.w;
        }
        // stage W tile (16 k x [80|80]) into ws[k][GAP(col)]
        {
            int r = rt;                 // 0..15
            int c4 = cg * 4;            // 0..76
            float4 v = *(const float4*)(Wl + (size_t)(k0 + r) * HC + c4);
            *(float4*)&ws[r * 176 + GAP(c4)] = v;
            float4 u = *(const float4*)(Wr + (size_t)(k0 + r) * HC + c4);
            *(float4*)&ws[r * 176 + GAP(c4 + 80)] = u;
        }
        __syncthreads();

        #pragma unroll 4
        for (int k = 0; k < 16; ++k) {
            const float* xk = &xs[k * 140 + rG0];
            float4 xa = *(const float4*)(xk);
            float4 xb = *(const float4*)(xk + 4);
            const float* wk = &ws[k * 176 + cG0];
            float4 wa = *(const float4*)(wk);
            float4 wb = *(const float4*)(wk + 4);
            float xv[8] = {xa.x, xa.y, xa.z, xa.w, xb.x, xb.y, xb.z, xb.w};
            #pragma unroll
            for (int i = 0; i < 8; ++i) {
                acc[i][0].x += xv[i] * wa.x;
                acc[i][0].y += xv[i] * wa.y;
                acc[i][0].z += xv[i] * wa.z;
                acc[i][0].w += xv[i] * wa.w;
                acc[i][1].x += xv[i] * wb.x;
                acc[i][1].y += xv[i] * wb.y;
                acc[i][1].z += xv[i] * wb.z;
                acc[i][1].w += xv[i] * wb.w;
            }
        }
    }

    float* Ybase = (cg < 10) ? (Yl + c0) : (Yr + (c0 - 80));
    #pragma unroll
    for (int i = 0; i < 8; ++i) {
        int n = base + r0 + i;
        if (n < N) {
            float* yp = Ybase + (size_t)n * HC;
            *(float4*)yp = acc[i][0];
            *(float4*)(yp + 4) = acc[i][1];
        }
    }
}

// ---------------- fused per-node attention + softmax + aggregate + elu ----------------
// block = 128 threads = 8 head-groups of 16 lanes (10 active each).
// 2 independent online-softmax chains (even/odd edges) merged at the end -> 2x load MLP.

__device__ __forceinline__ float edot16(float xlv, float xrv, float attv) {
    float t = xlv + xrv;
    t = (t > 0.f) ? t : 0.2f * t;          // leaky_relu
    float ev = t * attv;                   // attv pre-scaled by log2(e)
    ev += __shfl_xor(ev, 8, 16);
    ev += __shfl_xor(ev, 4, 16);
    ev += __shfl_xor(ev, 2, 16);
    ev += __shfl_xor(ev, 1, 16);
    return ev;
}

__global__ __launch_bounds__(128) void aggregate_kernel(
    const float* __restrict__ xl, const float* __restrict__ xr,
    const int* __restrict__ csr, const int* __restrict__ offsets,
    const float* __restrict__ att, const float* __restrict__ bias,
    float* __restrict__ xout, int N) {
    int n = blockIdx.x;
    int tid = threadIdx.x;
    int h = tid >> 4;
    int c = tid & 15;
    bool active = c < CC;
    int d = h * CC + (active ? c : CC - 1);
    float mask = active ? 1.f : 0.f;
    float attv = att[d] * mask * 1.4426950408889634f;   // log2(e): work in exp2 domain
    float xrv = xr[(size_t)n * HC + d];
    int beg = offsets[n], end = offsets[n + 1];

    // chain 0 seeded with the self loop
    float v0 = xl[(size_t)n * HC + d];
    float m0 = edot16(v0, xrv, attv), s0 = 1.f, a0 = v0;
    float m1 = -FLT_MAX, s1 = 0.f, a1 = 0.f;

    int i = beg;
    for (; i + 1 < end; i += 2) {
        int src0 = csr[i], src1 = csr[i + 1];
        float x0 = xl[(size_t)src0 * HC + d];
        float x1 = xl[(size_t)src1 * HC + d];
        float e0 = edot16(x0, xrv, attv);
        float e1 = edot16(x1, xrv, attv);
        float M0 = fmaxf(m0, e0);
        float sc0 = exp2f(m0 - M0), p0 = exp2f(e0 - M0);
        s0 = s0 * sc0 + p0; a0 = a0 * sc0 + p0 * x0; m0 = M0;
        float M1 = fmaxf(m1, e1);
        float sc1 = exp2f(m1 - M1), p1 = exp2f(e1 - M1);
        s1 = s1 * sc1 + p1; a1 = a1 * sc1 + p1 * x1; m1 = M1;
    }
    if (i < end) {
        int src0 = csr[i];
        float x0 = xl[(size_t)src0 * HC + d];
        float e0 = edot16(x0, xrv, attv);
        float M0 = fmaxf(m0, e0);
        float sc0 = exp2f(m0 - M0), p0 = exp2f(e0 - M0);
        s0 = s0 * sc0 + p0; a0 = a0 * sc0 + p0 * x0; m0 = M0;
    }
    // merge the two chains (exp2f(-FLT_MAX - M) underflows to 0 when chain 1 unused)
    float M = fmaxf(m0, m1);
    float f0 = exp2f(m0 - M), f1 = exp2f(m1 - M);
    float s = s0 * f0 + s1 * f1;
    float a = a0 * f0 + a1 * f1;

    if (active) {
        float o = a / s + bias[d];
        xout[(size_t)n * HC + h * CC + c] = (o > 0.f) ? o : (__expf(o) - 1.f);  // elu
    }
}

extern "C" void kernel_launch(void* const* d_in, const int* in_sizes, int n_in,
                              void* d_out, int out_size, void* d_ws, size_t ws_size,
                              hipStream_t stream) {
    int N = out_size / HC;       // 100000
    int E = in_sizes[1] / 2;     // 1000000
    int F = in_sizes[0] / N;     // 128

    const float* x   = (const float*)d_in[0];
    const int*   ei  = (const int*)d_in[1];
    const float* Wl[3]  = {(const float*)d_in[2], (const float*)d_in[6],  (const float*)d_in[10]};
    const float* Wr[3]  = {(const float*)d_in[3], (const float*)d_in[7],  (const float*)d_in[11]};
    const float* att[3] = {(const float*)d_in[4], (const float*)d_in[8],  (const float*)d_in[12]};
    const float* bb[3]  = {(const float*)d_in[5], (const float*)d_in[9],  (const float*)d_in[13]};

    size_t NF = (size_t)N * HC;
    float* xl = (float*)d_ws;
    float* xr = xl + NF;
    float* xb = xr + NF;
    int* counts  = (int*)(xb + NF);
    int* offsets = counts + (N + 1);
    int* cursor  = offsets + (N + 1);
    int* csr     = cursor + N;

    const int* srcv = ei;
    const int* dstv = ei + E;

    hipMemsetAsync(counts, 0, (size_t)(N + 1) * sizeof(int), stream);
    hist_kernel<<<1024, 256, 0, stream>>>(dstv, counts, E);
    scan_kernel<<<1, 1024, 0, stream>>>(counts, offsets, N);
    hipMemcpyAsync(cursor, offsets, (size_t)N * sizeof(int), hipMemcpyDeviceToDevice, stream);
    scatter_kernel<<<1024, 256, 0, stream>>>(srcv, dstv, cursor, csr, E);

    for (int l = 0; l < 3; ++l) {
        const float* xin = (l == 0) ? x : xb;
        int K = (l == 0) ? F : HC;
        gemm_big<<<(N + 127) / 128, 320, 0, stream>>>(xin, Wl[l], Wr[l], xl, xr, N, K);
        float* xout = (l == 2) ? (float*)d_out : xb;
        aggregate_kernel<<<N, 128, 0, stream>>>(xl, xr, csr, offsets, att[l], bb[l], xout, N);
    }
}

// Round 6
// 830.760 us; speedup vs baseline: 1.8078x; 1.1095x over previous
//
#include <hip/hip_runtime.h>
#include <cfloat>
#include <cmath>

#define HC 80   // H*C
#define HH 8    // heads
#define CC 10   // channels per head

// +4-float gap every 32 floats: spreads stride-32 column patterns across banks
#define GAP(c) ((c) + ((((c) >> 5)) << 2))

// ---------------- CSR build ----------------

__global__ void hist_kernel(const int* __restrict__ dst, int* __restrict__ counts, int E) {
    int i = blockIdx.x * blockDim.x + threadIdx.x;
    int stride = gridDim.x * blockDim.x;
    for (; i < E; i += stride) atomicAdd(&counts[dst[i]], 1);
}

__global__ void scan_kernel(const int* __restrict__ in, int* __restrict__ out, int n) {
    __shared__ int wsum[16];
    __shared__ int carry;
    if (threadIdx.x == 0) carry = 0;
    __syncthreads();
    int lane = threadIdx.x & 63, w = threadIdx.x >> 6;
    for (int base = 0; base < n; base += 1024) {
        int i = base + (int)threadIdx.x;
        int v = (i < n) ? in[i] : 0;
        int s = v;
        #pragma unroll
        for (int off = 1; off < 64; off <<= 1) {
            int t = __shfl_up(s, off, 64);
            if (lane >= off) s += t;
        }
        if (lane == 63) wsum[w] = s;
        __syncthreads();
        if (w == 0) {
            int ws = (lane < 16) ? wsum[lane] : 0;
            int ss = ws;
            #pragma unroll
            for (int off = 1; off < 16; off <<= 1) {
                int t = __shfl_up(ss, off, 64);
                if (lane >= off) ss += t;
            }
            if (lane < 16) wsum[lane] = ss - ws;
        }
        __syncthreads();
        int c = carry;
        if (i < n) out[i] = c + wsum[w] + s - v;
        __syncthreads();
        if (threadIdx.x == 1023) carry = c + wsum[15] + s;
    }
    __syncthreads();
    if (threadIdx.x == 0) out[n] = carry;
}

__global__ void scatter_kernel(const int* __restrict__ src, const int* __restrict__ dst,
                               int* __restrict__ cursor, int* __restrict__ csr, int E) {
    int i = blockIdx.x * blockDim.x + threadIdx.x;
    int stride = gridDim.x * blockDim.x;
    for (; i < E; i += stride) {
        int p = atomicAdd(&cursor[dst[i]], 1);
        csr[p] = src[i];
    }
}

// ---------------- dual GEMM: [Yl|Yr] = X @ [Wl|Wr]  (X:[N,K], W:[K,80] each) ----------------

__global__ __launch_bounds__(320) void gemm_big(
    const float* __restrict__ X, const float* __restrict__ Wl, const float* __restrict__ Wr,
    float* __restrict__ Yl, float* __restrict__ Yr, int N, int K)
{
    __shared__ float xs[16 * 140];   // GAP(127)=139
    __shared__ float ws[16 * 176];   // GAP(159)=175
    const int tid = threadIdx.x;
    const int rt = tid / 20;         // 0..15
    const int cg = tid - rt * 20;    // 0..19
    const int r0 = rt * 8;
    const int c0 = cg * 8;
    const int rG0 = GAP(r0);
    const int cG0 = GAP(c0);
    const int base = blockIdx.x * 128;

    float4 acc[8][2];
    #pragma unroll
    for (int i = 0; i < 8; ++i) {
        acc[i][0] = make_float4(0.f, 0.f, 0.f, 0.f);
        acc[i][1] = make_float4(0.f, 0.f, 0.f, 0.f);
    }

    for (int k0 = 0; k0 < K; k0 += 16) {
        __syncthreads();
        for (int idx = tid; idx < 512; idx += 320) {
            int r = idx >> 2, kc = (idx & 3) << 2;
            int n = base + r; if (n >= N) n = N - 1;
            float4 v = *(const float4*)(X + (size_t)n * K + k0 + kc);
            int rg = GAP(r);
            xs[(kc + 0) * 140 + rg] = v.x;
            xs[(kc + 1) * 140 + rg] = v.y;
            xs[(kc + 2) * 140 + rg] = v.z;
            xs[(kc + 3) * 140 + rg] = v.w;
        }
        {
            int r = rt;
            int c4 = cg * 4;
            float4 v = *(const float4*)(Wl + (size_t)(k0 + r) * HC + c4);
            *(float4*)&ws[r * 176 + GAP(c4)] = v;
            float4 u = *(const float4*)(Wr + (size_t)(k0 + r) * HC + c4);
            *(float4*)&ws[r * 176 + GAP(c4 + 80)] = u;
        }
        __syncthreads();

        #pragma unroll 4
        for (int k = 0; k < 16; ++k) {
            const float* xk = &xs[k * 140 + rG0];
            float4 xa = *(const float4*)(xk);
            float4 xb = *(const float4*)(xk + 4);
            const float* wk = &ws[k * 176 + cG0];
            float4 wa = *(const float4*)(wk);
            float4 wb = *(const float4*)(wk + 4);
            float xv[8] = {xa.x, xa.y, xa.z, xa.w, xb.x, xb.y, xb.z, xb.w};
            #pragma unroll
            for (int i = 0; i < 8; ++i) {
                acc[i][0].x += xv[i] * wa.x;
                acc[i][0].y += xv[i] * wa.y;
                acc[i][0].z += xv[i] * wa.z;
                acc[i][0].w += xv[i] * wa.w;
                acc[i][1].x += xv[i] * wb.x;
                acc[i][1].y += xv[i] * wb.y;
                acc[i][1].z += xv[i] * wb.z;
                acc[i][1].w += xv[i] * wb.w;
            }
        }
    }

    float* Ybase = (cg < 10) ? (Yl + c0) : (Yr + (c0 - 80));
    #pragma unroll
    for (int i = 0; i < 8; ++i) {
        int n = base + r0 + i;
        if (n < N) {
            float* yp = Ybase + (size_t)n * HC;
            *(float4*)yp = acc[i][0];
            *(float4*)(yp + 4) = acc[i][1];
        }
    }
}

// ---------------- fused per-node attention + softmax + aggregate + elu ----------------
// 1 wave per node, 8 lanes per head, float2 channels (lanes q<5 hold channels 2q,2q+1).
// Defer-max online softmax (THR=8 in exp2 domain): rescale branch ~never taken.

__device__ __forceinline__ float edot8(float2 xv, float2 xrv, float2 av) {
    float t0 = xv.x + xrv.x, t1 = xv.y + xrv.y;
    float l0 = 0.6f * t0 + 0.4f * fabsf(t0);   // leaky_relu(t, 0.2)
    float l1 = 0.6f * t1 + 0.4f * fabsf(t1);
    float e = l0 * av.x + l1 * av.y;           // av pre-scaled by log2(e)
    e += __shfl_xor(e, 4, 8);
    e += __shfl_xor(e, 2, 8);
    e += __shfl_xor(e, 1, 8);
    return e;
}

__device__ __forceinline__ void upd(float e, float2 xv, float& m, float& s, float2& a) {
    float diff = e - m;
    if (__builtin_expect(diff > 8.0f, 0)) {    // rare: new reference max
        float sc = exp2f(-diff);
        s = s * sc + 1.f;
        a.x = a.x * sc + xv.x;
        a.y = a.y * sc + xv.y;
        m = e;
    } else {                                    // common: p <= 2^8, no overflow
        float p = exp2f(diff);
        s += p;
        a.x += p * xv.x;
        a.y += p * xv.y;
    }
}

__global__ __launch_bounds__(128) void aggregate_kernel(
    const float* __restrict__ xl, const float* __restrict__ xr,
    const int* __restrict__ csr, const int* __restrict__ offsets,
    const float* __restrict__ att, const float* __restrict__ bias,
    float* __restrict__ xout, int N) {
    int wv = threadIdx.x >> 6;
    int lane = threadIdx.x & 63;
    int n = blockIdx.x * 2 + wv;
    if (n >= N) return;
    int h = lane >> 3;                 // head 0..7
    int q = lane & 7;                  // 0..7; q<5 active
    bool active = q < 5;
    int d = h * CC + (active ? 2 * q : 8);   // even -> 8B aligned
    const float L2E = 1.4426950408889634f;
    float2 av = make_float2(0.f, 0.f);
    if (active) { av = *(const float2*)(att + d); av.x *= L2E; av.y *= L2E; }
    float2 xrv = *(const float2*)(xr + (size_t)n * HC + d);
    int beg = offsets[n], end = offsets[n + 1];

    // chain 0 seeded with the self loop
    float2 v0 = *(const float2*)(xl + (size_t)n * HC + d);
    float m0 = edot8(v0, xrv, av);
    float s0 = 1.f; float2 a0 = v0;
    float m1 = -1e30f, s1 = 0.f; float2 a1 = make_float2(0.f, 0.f);

    int i = beg;
    for (; i + 1 < end; i += 2) {
        int i0 = csr[i], i1 = csr[i + 1];
        float2 x0 = *(const float2*)(xl + (size_t)i0 * HC + d);
        float2 x1 = *(const float2*)(xl + (size_t)i1 * HC + d);
        float e0 = edot8(x0, xrv, av);
        float e1 = edot8(x1, xrv, av);
        upd(e0, x0, m0, s0, a0);
        upd(e1, x1, m1, s1, a1);
    }
    if (i < end) {
        int i0 = csr[i];
        float2 x0 = *(const float2*)(xl + (size_t)i0 * HC + d);
        float e0 = edot8(x0, xrv, av);
        upd(e0, x0, m0, s0, a0);
    }
    // merge chains (exp2f(-1e30 - M) underflows to 0 when chain 1 unused)
    float M = fmaxf(m0, m1);
    float f0 = exp2f(m0 - M), f1 = exp2f(m1 - M);
    float s = s0 * f0 + s1 * f1;
    float ax = a0.x * f0 + a1.x * f1;
    float ay = a0.y * f0 + a1.y * f1;

    if (active) {
        float2 bv = *(const float2*)(bias + d);
        float o0 = ax / s + bv.x;
        float o1 = ay / s + bv.y;
        o0 = (o0 > 0.f) ? o0 : (__expf(o0) - 1.f);   // elu
        o1 = (o1 > 0.f) ? o1 : (__expf(o1) - 1.f);
        *(float2*)(xout + (size_t)n * HC + d) = make_float2(o0, o1);
    }
}

extern "C" void kernel_launch(void* const* d_in, const int* in_sizes, int n_in,
                              void* d_out, int out_size, void* d_ws, size_t ws_size,
                              hipStream_t stream) {
    int N = out_size / HC;       // 100000
    int E = in_sizes[1] / 2;     // 1000000
    int F = in_sizes[0] / N;     // 128

    const float* x   = (const float*)d_in[0];
    const int*   ei  = (const int*)d_in[1];
    const float* Wl[3]  = {(const float*)d_in[2], (const float*)d_in[6],  (const float*)d_in[10]};
    const float* Wr[3]  = {(const float*)d_in[3], (const float*)d_in[7],  (const float*)d_in[11]};
    const float* att[3] = {(const float*)d_in[4], (const float*)d_in[8],  (const float*)d_in[12]};
    const float* bb[3]  = {(const float*)d_in[5], (const float*)d_in[9],  (const float*)d_in[13]};

    size_t NF = (size_t)N * HC;
    float* xl = (float*)d_ws;
    float* xr = xl + NF;
    float* xb = xr + NF;
    int* counts  = (int*)(xb + NF);
    int* offsets = counts + (N + 1);
    int* cursor  = offsets + (N + 1);
    int* csr     = cursor + N;

    const int* srcv = ei;
    const int* dstv = ei + E;

    hipMemsetAsync(counts, 0, (size_t)(N + 1) * sizeof(int), stream);
    hist_kernel<<<1024, 256, 0, stream>>>(dstv, counts, E);
    scan_kernel<<<1, 1024, 0, stream>>>(counts, offsets, N);
    hipMemcpyAsync(cursor, offsets, (size_t)N * sizeof(int), hipMemcpyDeviceToDevice, stream);
    scatter_kernel<<<1024, 256, 0, stream>>>(srcv, dstv, cursor, csr, E);

    for (int l = 0; l < 3; ++l) {
        const float* xin = (l == 0) ? x : xb;
        int K = (l == 0) ? F : HC;
        gemm_big<<<(N + 127) / 128, 320, 0, stream>>>(xin, Wl[l], Wr[l], xl, xr, N, K);
        float* xout = (l == 2) ? (float*)d_out : xb;
        aggregate_kernel<<<(N + 1) / 2, 128, 0, stream>>>(xl, xr, csr, offsets, att[l], bb[l], xout, N);
    }
}

// Round 7
// 737.353 us; speedup vs baseline: 2.0368x; 1.1267x over previous
//
#include <hip/hip_runtime.h>
#include <cfloat>
#include <cmath>

#define HC 80   // H*C
#define HH 8    // heads
#define CC 10   // channels per head

// +4-float gap every 32 floats: spreads stride-32 column patterns across banks
#define GAP(c) ((c) + ((((c) >> 5)) << 2))

// ---------------- CSR build ----------------

__global__ void hist_kernel(const int* __restrict__ dst, int* __restrict__ counts, int E) {
    int i = blockIdx.x * blockDim.x + threadIdx.x;
    int stride = gridDim.x * blockDim.x;
    for (; i < E; i += stride) atomicAdd(&counts[dst[i]], 1);
}

__global__ void scan_kernel(const int* __restrict__ in, int* __restrict__ out, int n) {
    __shared__ int wsum[16];
    __shared__ int carry;
    if (threadIdx.x == 0) carry = 0;
    __syncthreads();
    int lane = threadIdx.x & 63, w = threadIdx.x >> 6;
    for (int base = 0; base < n; base += 1024) {
        int i = base + (int)threadIdx.x;
        int v = (i < n) ? in[i] : 0;
        int s = v;
        #pragma unroll
        for (int off = 1; off < 64; off <<= 1) {
            int t = __shfl_up(s, off, 64);
            if (lane >= off) s += t;
        }
        if (lane == 63) wsum[w] = s;
        __syncthreads();
        if (w == 0) {
            int ws = (lane < 16) ? wsum[lane] : 0;
            int ss = ws;
            #pragma unroll
            for (int off = 1; off < 16; off <<= 1) {
                int t = __shfl_up(ss, off, 64);
                if (lane >= off) ss += t;
            }
            if (lane < 16) wsum[lane] = ss - ws;
        }
        __syncthreads();
        int c = carry;
        if (i < n) out[i] = c + wsum[w] + s - v;
        __syncthreads();
        if (threadIdx.x == 1023) carry = c + wsum[15] + s;
    }
    __syncthreads();
    if (threadIdx.x == 0) out[n] = carry;
}

__global__ void scatter_kernel(const int* __restrict__ src, const int* __restrict__ dst,
                               int* __restrict__ cursor, int* __restrict__ csr, int E) {
    int i = blockIdx.x * blockDim.x + threadIdx.x;
    int stride = gridDim.x * blockDim.x;
    for (; i < E; i += stride) {
        int p = atomicAdd(&cursor[dst[i]], 1);
        csr[p] = src[i];
    }
}

// ---------------- dual GEMM: [Yl|Yr] = X @ [Wl|Wr]  (X:[N,K], W:[K,80] each) ----------------
// 320 threads, tile 128 rows x 160 cols, BK=16, thread tile 8x8.
// Thread map rt=tid&15, cg=tid>>4: within a wave, W reads are 4-address broadcast
// (free) and X reads are 16-address 2-way (free per m136) -> conflicts minimized.

__global__ __launch_bounds__(320) void gemm_big(
    const float* __restrict__ X, const float* __restrict__ Wl, const float* __restrict__ Wr,
    float* __restrict__ Yl, float* __restrict__ Yr, int N, int K)
{
    __shared__ float xs[16 * 140];   // GAP(127)=139
    __shared__ float ws[16 * 176];   // GAP(159)=175
    const int tid = threadIdx.x;
    const int rt = tid & 15;         // 0..15  (broadcast dim within wave: cols)
    const int cg = tid >> 4;         // 0..19
    const int r0 = rt * 8;
    const int c0 = cg * 8;
    const int rG0 = GAP(r0);
    const int cG0 = GAP(c0);
    const int base = blockIdx.x * 128;

    float4 acc[8][2];
    #pragma unroll
    for (int i = 0; i < 8; ++i) {
        acc[i][0] = make_float4(0.f, 0.f, 0.f, 0.f);
        acc[i][1] = make_float4(0.f, 0.f, 0.f, 0.f);
    }

    for (int k0 = 0; k0 < K; k0 += 16) {
        __syncthreads();
        for (int idx = tid; idx < 512; idx += 320) {
            int r = idx >> 2, kc = (idx & 3) << 2;
            int n = base + r; if (n >= N) n = N - 1;
            float4 v = *(const float4*)(X + (size_t)n * K + k0 + kc);
            int rg = GAP(r);
            xs[(kc + 0) * 140 + rg] = v.x;
            xs[(kc + 1) * 140 + rg] = v.y;
            xs[(kc + 2) * 140 + rg] = v.z;
            xs[(kc + 3) * 140 + rg] = v.w;
        }
        {
            int r = rt;
            int c4 = cg * 4;
            float4 v = *(const float4*)(Wl + (size_t)(k0 + r) * HC + c4);
            *(float4*)&ws[r * 176 + GAP(c4)] = v;
            float4 u = *(const float4*)(Wr + (size_t)(k0 + r) * HC + c4);
            *(float4*)&ws[r * 176 + GAP(c4 + 80)] = u;
        }
        __syncthreads();

        #pragma unroll 4
        for (int k = 0; k < 16; ++k) {
            const float* xk = &xs[k * 140 + rG0];
            float4 xa = *(const float4*)(xk);
            float4 xb = *(const float4*)(xk + 4);
            const float* wk = &ws[k * 176 + cG0];
            float4 wa = *(const float4*)(wk);
            float4 wb = *(const float4*)(wk + 4);
            float xv[8] = {xa.x, xa.y, xa.z, xa.w, xb.x, xb.y, xb.z, xb.w};
            #pragma unroll
            for (int i = 0; i < 8; ++i) {
                acc[i][0].x += xv[i] * wa.x;
                acc[i][0].y += xv[i] * wa.y;
                acc[i][0].z += xv[i] * wa.z;
                acc[i][0].w += xv[i] * wa.w;
                acc[i][1].x += xv[i] * wb.x;
                acc[i][1].y += xv[i] * wb.y;
                acc[i][1].z += xv[i] * wb.z;
                acc[i][1].w += xv[i] * wb.w;
            }
        }
    }

    float* Ybase = (cg < 10) ? (Yl + c0) : (Yr + (c0 - 80));
    #pragma unroll
    for (int i = 0; i < 8; ++i) {
        int n = base + r0 + i;
        if (n < N) {
            float* yp = Ybase + (size_t)n * HC;
            *(float4*)yp = acc[i][0];
            *(float4*)(yp + 4) = acc[i][1];
        }
    }
}

// ---------------- fused per-node attention + softmax + aggregate + elu ----------------
// Lane = head: 8-lane group per node, lane h holds head h's 10 channels in registers.
// Dot product + online softmax fully lane-local (zero shuffles). Wave = 8 nodes.
// Defer-max (THR=8, exp2 domain): rescale branch taken once (iter 0) then ~never.

__global__ __launch_bounds__(256) void aggregate_kernel(
    const float* __restrict__ xl, const float* __restrict__ xr,
    const int* __restrict__ csr, const int* __restrict__ offsets,
    const float* __restrict__ att, const float* __restrict__ bias,
    float* __restrict__ xout, int N) {
    const int tid = threadIdx.x;
    const int g = tid >> 3;            // group in block: 0..31
    const int h = tid & 7;             // head
    const int n = blockIdx.x * 32 + g;
    if (n >= N) return;
    const float L2E = 1.4426950408889634f;

    float attv[10], xrv[10];
    #pragma unroll
    for (int j = 0; j < 5; ++j) {
        float2 a = *(const float2*)(att + h * CC + 2 * j);
        attv[2 * j] = a.x * L2E; attv[2 * j + 1] = a.y * L2E;
        float2 r = *(const float2*)(xr + (size_t)n * HC + h * CC + 2 * j);
        xrv[2 * j] = r.x; xrv[2 * j + 1] = r.y;
    }

    const int beg = offsets[n], end = offsets[n + 1];
    float m = -1e30f, s = 0.f;
    float acc[10];
    #pragma unroll
    for (int j = 0; j < 10; ++j) acc[j] = 0.f;

    int i = beg - 1;                   // iteration -1 = self loop
    while (__any(i < end)) {
        if (i < end) {
            int src = (i < beg) ? n : csr[i];
            const float* xp = xl + (size_t)src * HC + h * CC;
            float xv[10];
            #pragma unroll
            for (int j = 0; j < 5; ++j) {
                float2 v = *(const float2*)(xp + 2 * j);
                xv[2 * j] = v.x; xv[2 * j + 1] = v.y;
            }
            float e = 0.f;
            #pragma unroll
            for (int j = 0; j < 10; ++j) {
                float t = xv[j] + xrv[j];
                float l = 0.6f * t + 0.4f * fabsf(t);   // leaky_relu(t, 0.2)
                e += l * attv[j];
            }
            float diff = e - m;
            if (__builtin_expect(diff > 8.0f, 0)) {     // new reference max (iter 0, then rare)
                float sc = exp2f(-diff);
                s = s * sc + 1.f;
                #pragma unroll
                for (int j = 0; j < 10; ++j) acc[j] = acc[j] * sc + xv[j];
                m = e;
            } else {
                float p = exp2f(diff);
                s += p;
                #pragma unroll
                for (int j = 0; j < 10; ++j) acc[j] += p * xv[j];
            }
        }
        ++i;
    }

    float inv = 1.f / s;
    float* op = xout + (size_t)n * HC + h * CC;
    #pragma unroll
    for (int j = 0; j < 5; ++j) {
        float2 b = *(const float2*)(bias + h * CC + 2 * j);
        float o0 = acc[2 * j] * inv + b.x;
        float o1 = acc[2 * j + 1] * inv + b.y;
        o0 = (o0 > 0.f) ? o0 : (__expf(o0) - 1.f);      // elu
        o1 = (o1 > 0.f) ? o1 : (__expf(o1) - 1.f);
        *(float2*)(op + 2 * j) = make_float2(o0, o1);
    }
}

extern "C" void kernel_launch(void* const* d_in, const int* in_sizes, int n_in,
                              void* d_out, int out_size, void* d_ws, size_t ws_size,
                              hipStream_t stream) {
    int N = out_size / HC;       // 100000
    int E = in_sizes[1] / 2;     // 1000000
    int F = in_sizes[0] / N;     // 128

    const float* x   = (const float*)d_in[0];
    const int*   ei  = (const int*)d_in[1];
    const float* Wl[3]  = {(const float*)d_in[2], (const float*)d_in[6],  (const float*)d_in[10]};
    const float* Wr[3]  = {(const float*)d_in[3], (const float*)d_in[7],  (const float*)d_in[11]};
    const float* att[3] = {(const float*)d_in[4], (const float*)d_in[8],  (const float*)d_in[12]};
    const float* bb[3]  = {(const float*)d_in[5], (const float*)d_in[9],  (const float*)d_in[13]};

    size_t NF = (size_t)N * HC;
    float* xl = (float*)d_ws;
    float* xr = xl + NF;
    float* xb = xr + NF;
    int* counts  = (int*)(xb + NF);
    int* offsets = counts + (N + 1);
    int* cursor  = offsets + (N + 1);
    int* csr     = cursor + N;

    const int* srcv = ei;
    const int* dstv = ei + E;

    hipMemsetAsync(counts, 0, (size_t)(N + 1) * sizeof(int), stream);
    hist_kernel<<<1024, 256, 0, stream>>>(dstv, counts, E);
    scan_kernel<<<1, 1024, 0, stream>>>(counts, offsets, N);
    hipMemcpyAsync(cursor, offsets, (size_t)N * sizeof(int), hipMemcpyDeviceToDevice, stream);
    scatter_kernel<<<1024, 256, 0, stream>>>(srcv, dstv, cursor, csr, E);

    for (int l = 0; l < 3; ++l) {
        const float* xin = (l == 0) ? x : xb;
        int K = (l == 0) ? F : HC;
        gemm_big<<<(N + 127) / 128, 320, 0, stream>>>(xin, Wl[l], Wr[l], xl, xr, N, K);
        float* xout = (l == 2) ? (float*)d_out : xb;
        aggregate_kernel<<<(N + 31) / 32, 256, 0, stream>>>(xl, xr, csr, offsets, att[l], bb[l], xout, N);
    }
}